// Round 9
// baseline (195.255 us; speedup 1.0000x reference)
//
#include <hip/hip_runtime.h>
#include <hip/hip_bf16.h>

typedef __attribute__((ext_vector_type(8))) short short8;
typedef __attribute__((ext_vector_type(4))) float floatx4;

#define K3   27
#define CIN  64
#define COUT 64
#define GSL  2      // ko slices per LDS group
#define NGRP 14     // 13 full groups of 2 + final group of 1
#define RING 6      // A-gather software-pipeline depth

// f32 -> bf16 bits, round-to-nearest-even
static __device__ __forceinline__ short bf16bits(float x) {
    unsigned u = __builtin_bit_cast(unsigned, x);
    u += 0x7FFFu + ((u >> 16) & 1u);
    return (short)(u >> 16);
}

__global__ void write_sentinel(float* out, float v) {
    if (threadIdx.x == 0 && blockIdx.x == 0) out[0] = v;
}

// ---- fused prep: blocks [0,27) permute weight, rest convert features ----
// wt2 short8-index within ko-slice: (kc*4+q)*64 + cout, element j = cin kc*32+q*8+j.
__global__ __launch_bounds__(256)
void prep_all(const float* __restrict__ feat, const float* __restrict__ w,
              short* __restrict__ featb, short* __restrict__ wt2, int n8) {
    __shared__ short tile[64][65];   // [cin][cout] (weight branch only)
    const int t = threadIdx.x;
    if (blockIdx.x < K3) {
        const int ko = blockIdx.x;
#pragma unroll
        for (int i = 0; i < 16; ++i) {
            int e = t + i * 256;
            tile[e >> 6][e & 63] = bf16bits(w[(size_t)ko * 4096 + e]);
        }
        __syncthreads();
        const int cout = t & 63, s = t >> 6;
#pragma unroll
        for (int h = 0; h < 2; ++h) {
            int s2 = s + h * 4, kc = s2 >> 2, q = s2 & 3;
            short8 v;
#pragma unroll
            for (int j = 0; j < 8; ++j) v[j] = tile[kc * 32 + q * 8 + j][cout];
            ((short8*)wt2)[(size_t)ko * 512 + s2 * 64 + cout] = v;
        }
    } else {
        int i = (blockIdx.x - K3) * 256 + t;
        if (i < n8) {
            const floatx4* src = (const floatx4*)feat + (size_t)i * 2;
            floatx4 v0 = src[0], v1 = src[1];
            short8 o;
            o[0] = bf16bits(v0.x); o[1] = bf16bits(v0.y);
            o[2] = bf16bits(v0.z); o[3] = bf16bits(v0.w);
            o[4] = bf16bits(v1.x); o[5] = bf16bits(v1.y);
            o[6] = bf16bits(v1.z); o[7] = bf16bits(v1.w);
            ((short8*)featb)[i] = o;
        }
    }
}

// ---- main: 32 KB LDS double buffer (14 barriers), A-gather ring depth 6 ----
__global__ __launch_bounds__(256, 4)
void spconv_mfma4(const short* __restrict__ featb,
                  const int* __restrict__ idx,
                  const short* __restrict__ wt2,
                  float* __restrict__ out, int M) {
    __shared__ short lds[2][GSL * 4096];    // 2 x 16 KB
    const int tid = threadIdx.x, lane = tid & 63, wave = tid >> 6;
    const int m0 = blockIdx.x * 64 + wave * 16;
    const int c = lane & 15, q = lane >> 4;

    // idx preload: 27 per lane (q-duplicated -> broadcast lines)
    const int rowA  = m0 + c;
    const int rsafe = rowA < M ? rowA : (M - 1);
    const long ib   = (long)rsafe * K3;
    int nb[K3];
#pragma unroll
    for (int j = 0; j < K3; ++j) nb[j] = idx[ib + j];
    if (rowA >= M) {
#pragma unroll
        for (int j = 0; j < K3; ++j) nb[j] = -1;
    }

#define GATHER(KO, A0, A1) do {                                         \
        int _n = nb[KO]; A0 = (short8)0; A1 = (short8)0;                \
        if (_n >= 0) {                                                  \
            const short8* _f = (const short8*)(featb + (size_t)_n * CIN); \
            A0 = _f[q]; A1 = _f[q + 4];                                 \
        } } while (0)

    const short8* wsrc = (const short8*)wt2;
    short8 tmp[2 * GSL];   // one group's staging regs (4 x 16 B / thread)

    // group 0 -> buf0 (via regs), group 1 -> regs (held through group-0 compute)
#pragma unroll
    for (int i = 0; i < 2 * GSL; ++i) tmp[i] = wsrc[i * 256 + tid];
#pragma unroll
    for (int i = 0; i < 2 * GSL; ++i) ((short8*)lds[0])[i * 256 + tid] = tmp[i];
#pragma unroll
    for (int i = 0; i < 2 * GSL; ++i) tmp[i] = wsrc[(size_t)GSL * 512 + i * 256 + tid];

    // A ring, depth RING
    short8 ar0[RING], ar1[RING];
#pragma unroll
    for (int r = 0; r < RING; ++r) GATHER(r, ar0[r], ar1[r]);

    floatx4 acc[4];
#pragma unroll
    for (int nt = 0; nt < 4; ++nt) acc[nt] = (floatx4)(0.0f);

    __syncthreads();   // buf0 visible

#pragma unroll
    for (int g = 0; g < NGRP; ++g) {
        const short8* B = (const short8*)lds[g & 1];
        const int jmax = (g == NGRP - 1) ? 1 : GSL;
#pragma unroll
        for (int j = 0; j < GSL; ++j) {
            if (j >= jmax) break;
            const int ko = g * GSL + j;
            const int slot = ko % RING;
            short8 a0 = ar0[slot], a1 = ar1[slot];
            if (ko + RING < K3) GATHER(ko + RING, ar0[slot], ar1[slot]);
#pragma unroll
            for (int nt = 0; nt < 4; ++nt) {
                short8 b0 = B[j * 512 + q * 64       + nt * 16 + c];  // kc=0
                short8 b1 = B[j * 512 + (4 + q) * 64 + nt * 16 + c];  // kc=1
                acc[nt] = __builtin_amdgcn_mfma_f32_16x16x32_bf16(a0, b0, acc[nt], 0, 0, 0);
                acc[nt] = __builtin_amdgcn_mfma_f32_16x16x32_bf16(a1, b1, acc[nt], 0, 0, 0);
            }
        }
        if (g + 1 < NGRP) {
            // write held group g+1 into the buffer freed at the previous barrier
#pragma unroll
            for (int i = 0; i < 2 * GSL; ++i)
                ((short8*)lds[(g + 1) & 1])[i * 256 + tid] = tmp[i];
            if (g + 2 < NGRP) {
#pragma unroll
                for (int i = 0; i < 2 * GSL; ++i) {
                    int slice = (g + 2) * GSL + (i >> 1);
                    if (slice > K3 - 1) slice = K3 - 1;   // clamp (last group)
                    tmp[i] = wsrc[(size_t)slice * 512 + (i & 1) * 256 + tid];
                }
            }
            __syncthreads();
        }
    }
#undef GATHER

    // C/D layout: col = lane&15, row = (lane>>4)*4 + reg
#pragma unroll
    for (int r = 0; r < 4; ++r) {
        int row = m0 + q * 4 + r;
        if (row < M) {
            float* o = out + (size_t)row * COUT;
#pragma unroll
            for (int nt = 0; nt < 4; ++nt)
                o[nt * 16 + c] = acc[nt][r];
        }
    }
}

// ---------- fallback (round-6 proven path, used if ws too small) ----------
__global__ void transpose_weight(const float* __restrict__ w,
                                 __hip_bfloat16* __restrict__ wt) {
    __shared__ short tile[64][65];
    const int k = blockIdx.x;
    const float* src = w + k * (CIN * COUT);
    short* dst = (short*)(wt + k * (CIN * COUT));
    const int t = threadIdx.x;
#pragma unroll
    for (int i = 0; i < 16; ++i) {
        int e = t + i * 256;
        tile[e >> 6][e & 63] = bf16bits(src[e]);
    }
    __syncthreads();
#pragma unroll
    for (int i = 0; i < 16; ++i) {
        int e = t + i * 256;
        dst[e] = tile[e & 63][e >> 6];
    }
}

__global__ __launch_bounds__(256, 4)
void spconv_mfma(const float* __restrict__ feat,
                 const int* __restrict__ idx,
                 const __hip_bfloat16* __restrict__ wt,
                 float* __restrict__ out,
                 int M, int N) {
    const int lane = threadIdx.x & 63;
    const int wave = threadIdx.x >> 6;
    const int m0   = blockIdx.x * 64 + wave * 16;
    const int c    = lane & 15;
    const int q    = lane >> 4;

    floatx4 acc[4];
#pragma unroll
    for (int nt = 0; nt < 4; ++nt) acc[nt] = (floatx4)(0.0f);

    const int  rowA  = m0 + c;
    const long ibase = (long)rowA * K3;

    for (int ko = 0; ko < K3; ++ko) {
        int nb = (rowA < M) ? idx[ibase + ko] : -1;
        short8 a0 = (short8)(0);
        short8 a1 = (short8)(0);
        if (nb >= 0 && nb < N) {
            const floatx4* f = (const floatx4*)(feat + (size_t)nb * CIN);
            floatx4 f0 = f[q * 2 + 0];
            floatx4 f1 = f[q * 2 + 1];
            floatx4 f2 = f[q * 2 + 8];
            floatx4 f3 = f[q * 2 + 9];
            a0[0] = bf16bits(f0.x); a0[1] = bf16bits(f0.y);
            a0[2] = bf16bits(f0.z); a0[3] = bf16bits(f0.w);
            a0[4] = bf16bits(f1.x); a0[5] = bf16bits(f1.y);
            a0[6] = bf16bits(f1.z); a0[7] = bf16bits(f1.w);
            a1[0] = bf16bits(f2.x); a1[1] = bf16bits(f2.y);
            a1[2] = bf16bits(f2.z); a1[3] = bf16bits(f2.w);
            a1[4] = bf16bits(f3.x); a1[5] = bf16bits(f3.y);
            a1[6] = bf16bits(f3.z); a1[7] = bf16bits(f3.w);
        }
        const short8* wr = (const short8*)(wt + ko * (CIN * COUT));
#pragma unroll
        for (int nt = 0; nt < 4; ++nt) {
            short8 b0 = wr[(nt * 16 + c) * 8 + q];
            short8 b1 = wr[(nt * 16 + c) * 8 + 4 + q];
            acc[nt] = __builtin_amdgcn_mfma_f32_16x16x32_bf16(a0, b0, acc[nt], 0, 0, 0);
            acc[nt] = __builtin_amdgcn_mfma_f32_16x16x32_bf16(a1, b1, acc[nt], 0, 0, 0);
        }
    }
#pragma unroll
    for (int r = 0; r < 4; ++r) {
        int row = m0 + q * 4 + r;
        if (row < M) {
            float* o = out + (size_t)row * COUT;
#pragma unroll
            for (int nt = 0; nt < 4; ++nt)
                o[nt * 16 + c] = acc[nt][r];
        }
    }
}

extern "C" void kernel_launch(void* const* d_in, const int* in_sizes, int n_in,
                              void* d_out, int out_size, void* d_ws, size_t ws_size,
                              hipStream_t stream) {
    float* out = (float*)d_out;

    float sentinel = 0.0f;
    if (n_in != 3)                                   sentinel = 1.0e6f;
    else if (in_sizes[2] != K3 * CIN * COUT)         sentinel = 2.0e6f;
    else if (in_sizes[1] % K3 != 0)                  sentinel = 3.0e6f;
    else if (in_sizes[1] / K3 != out_size / COUT)    sentinel = 4.0e6f;
    else if (in_sizes[0] % CIN != 0)                 sentinel = 5.0e6f;
    if (sentinel != 0.0f) {
        write_sentinel<<<1, 64, 0, stream>>>(out, sentinel);
        return;
    }

    const float* feat = (const float*)d_in[0];
    const int*   idx  = (const int*)d_in[1];
    const float* w    = (const float*)d_in[2];

    const int M = in_sizes[1] / K3;
    const int N = in_sizes[0] / CIN;

    const size_t featb_bytes = (size_t)N * CIN * 2;
    const size_t wt2_off     = (featb_bytes + 255) & ~(size_t)255;
    const size_t need        = wt2_off + (size_t)K3 * 512 * 16;

    if (ws_size >= need) {
        short* featb = (short*)d_ws;
        short* wt2   = (short*)((char*)d_ws + wt2_off);
        const int n8 = N * CIN / 8;
        const int prep_grid = K3 + (n8 + 255) / 256;
        prep_all<<<prep_grid, 256, 0, stream>>>(feat, w, featb, wt2, n8);
        const int grid = (M + 63) / 64;
        spconv_mfma4<<<grid, 256, 0, stream>>>(featb, idx, wt2, out, M);
    } else {
        __hip_bfloat16* wt = (__hip_bfloat16*)d_ws;
        transpose_weight<<<K3, 256, 0, stream>>>(w, wt);
        const int grid = (M + 63) / 64;
        spconv_mfma<<<grid, 256, 0, stream>>>(feat, idx, wt, out, M, N);
    }
}

// Round 10
// 183.821 us; speedup vs baseline: 1.0622x; 1.0622x over previous
//
#include <hip/hip_runtime.h>
#include <hip/hip_bf16.h>

typedef __attribute__((ext_vector_type(8))) short short8;
typedef __attribute__((ext_vector_type(4))) float floatx4;
typedef __attribute__((ext_vector_type(16))) float floatx16;

#define K3   27
#define CIN  64
#define COUT 64
#define GSL  2      // ko slices per LDS group (2 x 16 KB double buffer)
#define NGRP 14     // 13 full groups of 2 + final group of 1
#define RING 3      // A-gather software-pipeline depth

// f32 -> bf16 bits, round-to-nearest-even
static __device__ __forceinline__ short bf16bits(float x) {
    unsigned u = __builtin_bit_cast(unsigned, x);
    u += 0x7FFFu + ((u >> 16) & 1u);
    return (short)(u >> 16);
}

__global__ void write_sentinel(float* out, float v) {
    if (threadIdx.x == 0 && blockIdx.x == 0) out[0] = v;
}

// ---- fused prep: blocks [0,27) permute weight, rest convert features ----
// wt3 short8-slot within ko-slice: sh*64 + cout, holding k = sh*8 .. sh*8+7
// (k-major fragment order for mfma_32x32x16: lane reads slot (s*2+h)*64+cout).
__global__ __launch_bounds__(256)
void prep_all(const float* __restrict__ feat, const float* __restrict__ w,
              short* __restrict__ featb, short* __restrict__ wt3, int n8) {
    __shared__ short tile[64][65];   // [cin][cout] (weight branch only)
    const int t = threadIdx.x;
    if (blockIdx.x < K3) {
        const int ko = blockIdx.x;
#pragma unroll
        for (int i = 0; i < 16; ++i) {
            int e = t + i * 256;
            tile[e >> 6][e & 63] = bf16bits(w[(size_t)ko * 4096 + e]);
        }
        __syncthreads();
        const int cout = t & 63, s = t >> 6;
#pragma unroll
        for (int h = 0; h < 2; ++h) {
            int sh = s + h * 4;          // 0..7 : k-block
            short8 v;
#pragma unroll
            for (int j = 0; j < 8; ++j) v[j] = tile[sh * 8 + j][cout];
            ((short8*)wt3)[(size_t)ko * 512 + sh * 64 + cout] = v;
        }
    } else {
        int i = (blockIdx.x - K3) * 256 + t;
        if (i < n8) {
            const floatx4* src = (const floatx4*)feat + (size_t)i * 2;
            floatx4 v0 = src[0], v1 = src[1];
            short8 o;
            o[0] = bf16bits(v0.x); o[1] = bf16bits(v0.y);
            o[2] = bf16bits(v0.z); o[3] = bf16bits(v0.w);
            o[4] = bf16bits(v1.x); o[5] = bf16bits(v1.y);
            o[6] = bf16bits(v1.z); o[7] = bf16bits(v1.w);
            ((short8*)featb)[i] = o;
        }
    }
}

// ---- main: 32x32x16 MFMA, 32 rows/wave (128/block) -> half B-LDS traffic/row ----
__global__ __launch_bounds__(256, 3)
void spconv_mfma5(const short* __restrict__ featb,
                  const int* __restrict__ idx,
                  const short* __restrict__ wt3,
                  float* __restrict__ out, int M) {
    __shared__ short lds[2][GSL * 4096];    // 2 x 16 KB
    const int tid = threadIdx.x, lane = tid & 63, wave = tid >> 6;
    const int m0 = blockIdx.x * 128 + wave * 32;
    const int n31 = lane & 31;   // A-row within 32 / B-cout within tile
    const int h   = lane >> 5;   // k-half selector

    // idx preload: 27 per lane (h-duplicated -> broadcast lines)
    const int rowA  = m0 + n31;
    const int rsafe = rowA < M ? rowA : (M - 1);
    const long ib   = (long)rsafe * K3;
    int nb[K3];
#pragma unroll
    for (int j = 0; j < K3; ++j) nb[j] = idx[ib + j];
    if (rowA >= M) {
#pragma unroll
        for (int j = 0; j < K3; ++j) nb[j] = -1;
    }

    // A-frag: af[s] holds k = s*16 + h*8 + j  -> row short8-slot s*2+h
#define GATHER(KO, AR) do {                                              \
        int _n = nb[KO];                                                 \
        AR[0] = (short8)0; AR[1] = (short8)0;                            \
        AR[2] = (short8)0; AR[3] = (short8)0;                            \
        if (_n >= 0) {                                                   \
            const short8* _f = (const short8*)(featb + (size_t)_n * CIN);\
            AR[0] = _f[h]; AR[1] = _f[2 + h];                            \
            AR[2] = _f[4 + h]; AR[3] = _f[6 + h];                        \
        } } while (0)

    const short8* wsrc = (const short8*)wt3;
    short8 tmp[2 * GSL];   // one group's staging regs (4 x 16 B / thread)

    // group 0 -> buf0 (via regs), group 1 -> regs (held through group-0 compute)
#pragma unroll
    for (int i = 0; i < 2 * GSL; ++i) tmp[i] = wsrc[i * 256 + tid];
#pragma unroll
    for (int i = 0; i < 2 * GSL; ++i) ((short8*)lds[0])[i * 256 + tid] = tmp[i];
#pragma unroll
    for (int i = 0; i < 2 * GSL; ++i) tmp[i] = wsrc[(size_t)GSL * 512 + i * 256 + tid];

    // A ring, depth RING
    short8 ar[RING][4];
#pragma unroll
    for (int r = 0; r < RING; ++r) GATHER(r, ar[r]);

    floatx16 acc[2];
#pragma unroll
    for (int nt = 0; nt < 2; ++nt) acc[nt] = (floatx16)(0.0f);

    __syncthreads();   // buf0 visible

#pragma unroll
    for (int g = 0; g < NGRP; ++g) {
        const short8* B = (const short8*)lds[g & 1];
        const int jmax = (g == NGRP - 1) ? 1 : GSL;
#pragma unroll
        for (int j = 0; j < GSL; ++j) {
            if (j >= jmax) break;
            const int ko = g * GSL + j;
            const int slot = ko % RING;
            short8 a0 = ar[slot][0], a1 = ar[slot][1];
            short8 a2 = ar[slot][2], a3 = ar[slot][3];
            if (ko + RING < K3) GATHER(ko + RING, ar[slot]);
#pragma unroll
            for (int nt = 0; nt < 2; ++nt) {
                const int cb = j * 512 + nt * 32 + n31;
                short8 b0 = B[cb + (0 * 2 + h) * 64];
                short8 b1 = B[cb + (1 * 2 + h) * 64];
                short8 b2 = B[cb + (2 * 2 + h) * 64];
                short8 b3 = B[cb + (3 * 2 + h) * 64];
                acc[nt] = __builtin_amdgcn_mfma_f32_32x32x16_bf16(a0, b0, acc[nt], 0, 0, 0);
                acc[nt] = __builtin_amdgcn_mfma_f32_32x32x16_bf16(a1, b1, acc[nt], 0, 0, 0);
                acc[nt] = __builtin_amdgcn_mfma_f32_32x32x16_bf16(a2, b2, acc[nt], 0, 0, 0);
                acc[nt] = __builtin_amdgcn_mfma_f32_32x32x16_bf16(a3, b3, acc[nt], 0, 0, 0);
            }
        }
        if (g + 1 < NGRP) {
#pragma unroll
            for (int i = 0; i < 2 * GSL; ++i)
                ((short8*)lds[(g + 1) & 1])[i * 256 + tid] = tmp[i];
            if (g + 2 < NGRP) {
#pragma unroll
                for (int i = 0; i < 2 * GSL; ++i) {
                    int slice = (g + 2) * GSL + (i >> 1);
                    if (slice > K3 - 1) slice = K3 - 1;   // clamp (last group)
                    tmp[i] = wsrc[(size_t)slice * 512 + (i & 1) * 256 + tid];
                }
            }
            __syncthreads();
        }
    }
#undef GATHER

    // C/D layout (m74/m101): col = lane&31, row = (reg&3) + 8*(reg>>2) + 4*(lane>>5)
#pragma unroll
    for (int reg = 0; reg < 16; ++reg) {
        int row = m0 + (reg & 3) + 8 * (reg >> 2) + 4 * h;
        if (row < M) {
            float* o = out + (size_t)row * COUT + n31;
            o[0]  = acc[0][reg];
            o[32] = acc[1][reg];
        }
    }
}

// ---------- fallback (round-6 proven path, used if ws too small) ----------
__global__ void transpose_weight(const float* __restrict__ w,
                                 __hip_bfloat16* __restrict__ wt) {
    __shared__ short tile[64][65];
    const int k = blockIdx.x;
    const float* src = w + k * (CIN * COUT);
    short* dst = (short*)(wt + k * (CIN * COUT));
    const int t = threadIdx.x;
#pragma unroll
    for (int i = 0; i < 16; ++i) {
        int e = t + i * 256;
        tile[e >> 6][e & 63] = bf16bits(src[e]);
    }
    __syncthreads();
#pragma unroll
    for (int i = 0; i < 16; ++i) {
        int e = t + i * 256;
        dst[e] = tile[e & 63][e >> 6];
    }
}

__global__ __launch_bounds__(256, 4)
void spconv_mfma(const float* __restrict__ feat,
                 const int* __restrict__ idx,
                 const __hip_bfloat16* __restrict__ wt,
                 float* __restrict__ out,
                 int M, int N) {
    const int lane = threadIdx.x & 63;
    const int wave = threadIdx.x >> 6;
    const int m0   = blockIdx.x * 64 + wave * 16;
    const int c    = lane & 15;
    const int q    = lane >> 4;

    floatx4 acc[4];
#pragma unroll
    for (int nt = 0; nt < 4; ++nt) acc[nt] = (floatx4)(0.0f);

    const int  rowA  = m0 + c;
    const long ibase = (long)rowA * K3;

    for (int ko = 0; ko < K3; ++ko) {
        int nb = (rowA < M) ? idx[ibase + ko] : -1;
        short8 a0 = (short8)(0);
        short8 a1 = (short8)(0);
        if (nb >= 0 && nb < N) {
            const floatx4* f = (const floatx4*)(feat + (size_t)nb * CIN);
            floatx4 f0 = f[q * 2 + 0];
            floatx4 f1 = f[q * 2 + 1];
            floatx4 f2 = f[q * 2 + 8];
            floatx4 f3 = f[q * 2 + 9];
            a0[0] = bf16bits(f0.x); a0[1] = bf16bits(f0.y);
            a0[2] = bf16bits(f0.z); a0[3] = bf16bits(f0.w);
            a0[4] = bf16bits(f1.x); a0[5] = bf16bits(f1.y);
            a0[6] = bf16bits(f1.z); a0[7] = bf16bits(f1.w);
            a1[0] = bf16bits(f2.x); a1[1] = bf16bits(f2.y);
            a1[2] = bf16bits(f2.z); a1[3] = bf16bits(f2.w);
            a1[4] = bf16bits(f3.x); a1[5] = bf16bits(f3.y);
            a1[6] = bf16bits(f3.z); a1[7] = bf16bits(f3.w);
        }
        const short8* wr = (const short8*)(wt + ko * (CIN * COUT));
#pragma unroll
        for (int nt = 0; nt < 4; ++nt) {
            short8 b0 = wr[(nt * 16 + c) * 8 + q];
            short8 b1 = wr[(nt * 16 + c) * 8 + 4 + q];
            acc[nt] = __builtin_amdgcn_mfma_f32_16x16x32_bf16(a0, b0, acc[nt], 0, 0, 0);
            acc[nt] = __builtin_amdgcn_mfma_f32_16x16x32_bf16(a1, b1, acc[nt], 0, 0, 0);
        }
    }
#pragma unroll
    for (int r = 0; r < 4; ++r) {
        int row = m0 + q * 4 + r;
        if (row < M) {
            float* o = out + (size_t)row * COUT;
#pragma unroll
            for (int nt = 0; nt < 4; ++nt)
                o[nt * 16 + c] = acc[nt][r];
        }
    }
}

extern "C" void kernel_launch(void* const* d_in, const int* in_sizes, int n_in,
                              void* d_out, int out_size, void* d_ws, size_t ws_size,
                              hipStream_t stream) {
    float* out = (float*)d_out;

    float sentinel = 0.0f;
    if (n_in != 3)                                   sentinel = 1.0e6f;
    else if (in_sizes[2] != K3 * CIN * COUT)         sentinel = 2.0e6f;
    else if (in_sizes[1] % K3 != 0)                  sentinel = 3.0e6f;
    else if (in_sizes[1] / K3 != out_size / COUT)    sentinel = 4.0e6f;
    else if (in_sizes[0] % CIN != 0)                 sentinel = 5.0e6f;
    if (sentinel != 0.0f) {
        write_sentinel<<<1, 64, 0, stream>>>(out, sentinel);
        return;
    }

    const float* feat = (const float*)d_in[0];
    const int*   idx  = (const int*)d_in[1];
    const float* w    = (const float*)d_in[2];

    const int M = in_sizes[1] / K3;
    const int N = in_sizes[0] / CIN;

    const size_t featb_bytes = (size_t)N * CIN * 2;
    const size_t wt_off      = (featb_bytes + 255) & ~(size_t)255;
    const size_t need        = wt_off + (size_t)K3 * 512 * 16;

    if (ws_size >= need) {
        short* featb = (short*)d_ws;
        short* wt3   = (short*)((char*)d_ws + wt_off);
        const int n8 = N * CIN / 8;
        const int prep_grid = K3 + (n8 + 255) / 256;
        prep_all<<<prep_grid, 256, 0, stream>>>(feat, w, featb, wt3, n8);
        const int grid = (M + 127) / 128;
        spconv_mfma5<<<grid, 256, 0, stream>>>(featb, idx, wt3, out, M);
    } else {
        __hip_bfloat16* wt = (__hip_bfloat16*)d_ws;
        transpose_weight<<<K3, 256, 0, stream>>>(w, wt);
        const int grid = (M + 63) / 64;
        spconv_mfma<<<grid, 256, 0, stream>>>(feat, idx, wt, out, M, N);
    }
}